// Round 3
// baseline (749.732 us; speedup 1.0000x reference)
//
#include <hip/hip_runtime.h>
#include <hip/hip_bf16.h>

// Problem constants: B=1, S=1024, D=1024, F=4096, E=8
#define TOK 1024
#define DIM 1024
#define FF  4096
#define NE  8
#define EPSV 1e-5f
#define MAX_TILES 72
#define BUCKET_STRIDE 1040   // 1024 + pad slack, per expert

typedef __attribute__((ext_vector_type(8))) short short8;   // 8 bf16 = 4 VGPRs
typedef __attribute__((ext_vector_type(4))) float floatx4;

// -------- workspace layout (bytes) --------
#define OFF_HNORM  0
#define OFF_H1     (TOK*DIM*2)
#define OFF_ALPHA  (OFF_H1 + TOK*FF*2)
#define OFF_CNT    (OFF_ALPHA + TOK*4)
#define OFF_NT     (OFF_CNT + NE*4)
#define OFF_TILES  (OFF_NT + 4)
#define OFF_BUCKET (OFF_TILES + MAX_TILES*4)
#define OFF_FLAGS  (OFF_BUCKET + NE*BUCKET_STRIDE*4)   // 9 ints: 8 per-input flags + OR

struct Ptr8 { const void* p[8]; };

// ---- dual-dtype helpers (flag: 1 = buffer is float32, 0 = bf16) ----
__device__ __forceinline__ float ldf(const void* p, size_t i, int f32) {
    if (f32) return ((const float*)p)[i];
    union { unsigned u; float f; } v;
    v.u = ((unsigned)((const unsigned short*)p)[i]) << 16;
    return v.f;
}

__device__ __forceinline__ short8 ldfrag8(const void* p, size_t i, int f32) {
    if (!f32) return *(const short8*)((const short*)p + i);
    const float* fp = (const float*)p + i;
    short8 r;
    #pragma unroll
    for (int j = 0; j < 8; j++) {
        unsigned u = __float_as_uint(fp[j]);
        r[j] = (short)((u + 0x7FFFu + ((u >> 16) & 1u)) >> 16);  // RNE to bf16
    }
    return r;
}

__device__ __forceinline__ void stout(void* p, size_t i, float v, int f32) {
    if (f32) ((float*)p)[i] = v;
    else ((__hip_bfloat16*)p)[i] = __float2bfloat16(v);
}

// Zero cnt + classify each input buffer's dtype by bit-pattern scan.
__global__ void k_init(Ptr8 ptrs, int* __restrict__ cnt, int* __restrict__ flags) {
    const int tid = threadIdx.x;
    if (tid < NE) cnt[tid] = 0;
    if (tid < 8) {
        const unsigned* w = (const unsigned*)ptrs.p[tid];
        int f32 = 0;
        for (int i = 0; i < 64; i++) {
            const unsigned v = w[i];
            if (v == 0x3F800000u) { f32 = 1; break; }   // exact f32 1.0 (e.g. gamma=ones)
            const unsigned lo = v & 0xFFFFu;
            if (lo != 0) {
                const unsigned e = (lo >> 7) & 0xFFu;
                if (e < 0x60u || e > 0x9Fu) { f32 = 1; break; }  // implausible bf16 exponent
            }
        }
        flags[tid] = f32;
    }
    __syncthreads();
    if (tid == 0) {
        int o = 0;
        for (int i = 0; i < 8; i++) o |= flags[i];
        flags[8] = o;   // output dtype via promotion: any f32 input -> f32 out
    }
}

// One block (256 threads) per token: routing scores + argmax + sigmoid gate + LN.
__global__ __launch_bounds__(256) void k_route_ln(
    const void* __restrict__ x,
    const void* __restrict__ cent,
    const void* __restrict__ gamma,
    const void* __restrict__ beta,
    const int* __restrict__ flags,
    __hip_bfloat16* __restrict__ hnorm,
    float* __restrict__ alpha,
    int* __restrict__ cnt,
    int* __restrict__ bucket)
{
    __shared__ float centS[NE * DIM];
    __shared__ float part[4][10];
    __shared__ float bc[3];   // mu, rstd, expert-bits

    const int tid = threadIdx.x;
    const int t = blockIdx.x;
    const int fx = flags[0], fc = flags[1], fg = flags[2], fb = flags[3];

    // stage all 8 centroids into LDS as f32
    for (int i = tid; i < NE * DIM; i += 256) centS[i] = ldf(cent, i, fc);

    // this token's row: 4 elements per thread, coalesced
    float xv[4];
    #pragma unroll
    for (int i = 0; i < 4; i++)
        xv[i] = ldf(x, (size_t)t * DIM + tid + 256 * i, fx);

    __syncthreads();

    float s = 0.f, sq = 0.f, c[NE];
    #pragma unroll
    for (int e = 0; e < NE; e++) c[e] = 0.f;

    #pragma unroll
    for (int i = 0; i < 4; i++) {
        const int d = tid + 256 * i;
        const float f = xv[i];
        s += f; sq += f * f;
        #pragma unroll
        for (int e = 0; e < NE; e++)
            c[e] += f * centS[e * DIM + d];
    }

    // wave(64) butterfly reduce of 10 values
    #pragma unroll
    for (int o = 32; o > 0; o >>= 1) {
        s  += __shfl_xor(s, o);
        sq += __shfl_xor(sq, o);
        #pragma unroll
        for (int e = 0; e < NE; e++) c[e] += __shfl_xor(c[e], o);
    }
    const int wid = tid >> 6, lid = tid & 63;
    if (lid == 0) {
        part[wid][0] = s; part[wid][1] = sq;
        #pragma unroll
        for (int e = 0; e < NE; e++) part[wid][2 + e] = c[e];
    }
    __syncthreads();

    if (tid == 0) {
        float S = 0.f, SQ = 0.f, C[NE];
        #pragma unroll
        for (int e = 0; e < NE; e++) C[e] = 0.f;
        for (int w = 0; w < 4; w++) {
            S += part[w][0]; SQ += part[w][1];
            #pragma unroll
            for (int e = 0; e < NE; e++) C[e] += part[w][2 + e];
        }
        const float mu = S / (float)DIM;
        const float var = SQ / (float)DIM - mu * mu;
        const float rstd = rsqrtf(var + EPSV);
        int be = 0; float bs = C[0];
        #pragma unroll
        for (int e = 1; e < NE; e++)
            if (C[e] > bs) { bs = C[e]; be = e; }   // first-occurrence argmax
        alpha[t] = 1.f / (1.f + expf(-bs));
        const int pos = atomicAdd(&cnt[be], 1);
        bucket[be * BUCKET_STRIDE + pos] = t;
        bc[0] = mu; bc[1] = rstd; bc[2] = __int_as_float(be);
    }
    __syncthreads();

    const float mu = bc[0], rstd = bc[1];
    const int e = __float_as_int(bc[2]);
    #pragma unroll
    for (int i = 0; i < 4; i++) {
        const int d = tid + 256 * i;
        const float g = ldf(gamma, (size_t)e * DIM + d, fg);
        const float b = ldf(beta,  (size_t)e * DIM + d, fb);
        const float h = (xv[i] - mu) * rstd * g + b;
        hnorm[(size_t)t * DIM + d] = __float2bfloat16(h);
    }
}

// Single thread: build tile list, pad buckets to multiples of 16.
__global__ void k_plan(const int* __restrict__ cnt, int* __restrict__ bucket,
                       int* __restrict__ tiles, int* __restrict__ numTiles)
{
    if (threadIdx.x == 0 && blockIdx.x == 0) {
        int nt = 0;
        for (int e = 0; e < NE; e++) {
            const int n = cnt[e];
            const int mt = (n + 15) >> 4;
            const int fill = (n > 0) ? bucket[e * BUCKET_STRIDE] : 0;
            for (int i = n; i < mt * 16; i++) bucket[e * BUCKET_STRIDE + i] = fill;
            for (int i = 0; i < mt; i++) tiles[nt++] = (e << 16) | (i * 16);
        }
        *numTiles = nt;
    }
}

// Grouped GEMM FF1: h1[t,f] = relu(hnorm[t,:] . W1[e,f,:] + b1[e,f])
__global__ __launch_bounds__(256) void k_ff1(
    const __hip_bfloat16* __restrict__ hnorm,
    const void* __restrict__ W1,
    const void* __restrict__ b1,
    const int* __restrict__ flags,
    __hip_bfloat16* __restrict__ h1,
    const int* __restrict__ tiles,
    const int* __restrict__ numTiles,
    const int* __restrict__ cnt,
    const int* __restrict__ bucket)
{
    const int tile = blockIdx.x >> 4;
    if (tile >= *numTiles) return;
    const int fW = flags[4], fB = flags[5];
    const int nb = blockIdx.x & 15;
    const int td = tiles[tile];
    const int e = td >> 16;
    const int mbase = td & 0xffff;
    const int ne = cnt[e];

    const int wid = threadIdx.x >> 6;
    const int lane = threadIdx.x & 63;
    const int mr = lane & 15;     // A row / D col index
    const int q  = lane >> 4;     // k-quad (8 elements each)

    const int tok = bucket[e * BUCKET_STRIDE + mbase + mr];
    const short* A = (const short*)hnorm + (size_t)tok * DIM + q * 8;
    const int n0 = nb * 256 + wid * 64;
    const size_t Brow = ((size_t)e * FF + n0 + mr) * DIM + q * 8;

    floatx4 acc[4];
    #pragma unroll
    for (int j = 0; j < 4; j++) acc[j] = (floatx4){0.f, 0.f, 0.f, 0.f};

    for (int k = 0; k < DIM; k += 32) {
        const short8 a  = *(const short8*)(A + k);
        const short8 b0 = ldfrag8(W1, Brow + k, fW);
        const short8 b1v = ldfrag8(W1, Brow + (size_t)16 * DIM + k, fW);
        const short8 b2v = ldfrag8(W1, Brow + (size_t)32 * DIM + k, fW);
        const short8 b3v = ldfrag8(W1, Brow + (size_t)48 * DIM + k, fW);
        acc[0] = __builtin_amdgcn_mfma_f32_16x16x32_bf16(a, b0,  acc[0], 0, 0, 0);
        acc[1] = __builtin_amdgcn_mfma_f32_16x16x32_bf16(a, b1v, acc[1], 0, 0, 0);
        acc[2] = __builtin_amdgcn_mfma_f32_16x16x32_bf16(a, b2v, acc[2], 0, 0, 0);
        acc[3] = __builtin_amdgcn_mfma_f32_16x16x32_bf16(a, b3v, acc[3], 0, 0, 0);
    }

    const int col = lane & 15;
    #pragma unroll
    for (int r = 0; r < 4; r++) {
        const int mi = q * 4 + r;
        const int slot = mbase + mi;
        if (slot < ne) {
            const int tr = bucket[e * BUCKET_STRIDE + slot];
            #pragma unroll
            for (int j = 0; j < 4; j++) {
                const int f = n0 + j * 16 + col;
                float v = acc[j][r] + ldf(b1, (size_t)e * FF + f, fB);
                v = v > 0.f ? v : 0.f;
                h1[(size_t)tr * FF + f] = __float2bfloat16(v);
            }
        }
    }
}

// Grouped GEMM FF2 + fused gate/residual:
// out[t,d] = x[t,d] + alpha[t] * (h1[t,:] . W2[e,d,:] + b2[e,d])
__global__ __launch_bounds__(256) void k_ff2(
    const __hip_bfloat16* __restrict__ h1,
    const void* __restrict__ W2,
    const void* __restrict__ b2,
    const void* __restrict__ x,
    const int* __restrict__ flags,
    const float* __restrict__ alpha,
    void* __restrict__ out,
    const int* __restrict__ tiles,
    const int* __restrict__ numTiles,
    const int* __restrict__ cnt,
    const int* __restrict__ bucket)
{
    const int tile = blockIdx.x >> 2;
    if (tile >= *numTiles) return;
    const int fW = flags[6], fB = flags[7], fx = flags[0], fo = flags[8];
    const int nb = blockIdx.x & 3;
    const int td = tiles[tile];
    const int e = td >> 16;
    const int mbase = td & 0xffff;
    const int ne = cnt[e];

    const int wid = threadIdx.x >> 6;
    const int lane = threadIdx.x & 63;
    const int mr = lane & 15;
    const int q  = lane >> 4;

    const int tok = bucket[e * BUCKET_STRIDE + mbase + mr];
    const short* A = (const short*)h1 + (size_t)tok * FF + q * 8;
    const int n0 = nb * 256 + wid * 64;
    const size_t Brow = ((size_t)e * DIM + n0 + mr) * FF + q * 8;

    floatx4 acc[4];
    #pragma unroll
    for (int j = 0; j < 4; j++) acc[j] = (floatx4){0.f, 0.f, 0.f, 0.f};

    for (int k = 0; k < FF; k += 32) {
        const short8 a  = *(const short8*)(A + k);
        const short8 b0 = ldfrag8(W2, Brow + k, fW);
        const short8 b1v = ldfrag8(W2, Brow + (size_t)16 * FF + k, fW);
        const short8 b2v = ldfrag8(W2, Brow + (size_t)32 * FF + k, fW);
        const short8 b3v = ldfrag8(W2, Brow + (size_t)48 * FF + k, fW);
        acc[0] = __builtin_amdgcn_mfma_f32_16x16x32_bf16(a, b0,  acc[0], 0, 0, 0);
        acc[1] = __builtin_amdgcn_mfma_f32_16x16x32_bf16(a, b1v, acc[1], 0, 0, 0);
        acc[2] = __builtin_amdgcn_mfma_f32_16x16x32_bf16(a, b2v, acc[2], 0, 0, 0);
        acc[3] = __builtin_amdgcn_mfma_f32_16x16x32_bf16(a, b3v, acc[3], 0, 0, 0);
    }

    const int col = lane & 15;
    #pragma unroll
    for (int r = 0; r < 4; r++) {
        const int mi = q * 4 + r;
        const int slot = mbase + mi;
        if (slot < ne) {
            const int tr = bucket[e * BUCKET_STRIDE + slot];
            const float al = alpha[tr];
            #pragma unroll
            for (int j = 0; j < 4; j++) {
                const int d = n0 + j * 16 + col;
                const float xb = ldf(x, (size_t)tr * DIM + d, fx);
                const float v = xb + al * (acc[j][r] + ldf(b2, (size_t)e * DIM + d, fB));
                stout(out, (size_t)tr * DIM + d, v, fo);
            }
        }
    }
}

extern "C" void kernel_launch(void* const* d_in, const int* in_sizes, int n_in,
                              void* d_out, int out_size, void* d_ws, size_t ws_size,
                              hipStream_t stream) {
    char* ws = (char*)d_ws;
    __hip_bfloat16* hnorm = (__hip_bfloat16*)(ws + OFF_HNORM);
    __hip_bfloat16* h1    = (__hip_bfloat16*)(ws + OFF_H1);
    float* alpha          = (float*)(ws + OFF_ALPHA);
    int* cnt              = (int*)(ws + OFF_CNT);
    int* numTiles         = (int*)(ws + OFF_NT);
    int* tiles            = (int*)(ws + OFF_TILES);
    int* bucket           = (int*)(ws + OFF_BUCKET);
    int* flags            = (int*)(ws + OFF_FLAGS);

    Ptr8 ptrs;
    for (int i = 0; i < 8; i++) ptrs.p[i] = d_in[i];

    k_init<<<1, 64, 0, stream>>>(ptrs, cnt, flags);
    k_route_ln<<<TOK, 256, 0, stream>>>(d_in[0], d_in[1], d_in[2], d_in[3], flags,
                                        hnorm, alpha, cnt, bucket);
    k_plan<<<1, 64, 0, stream>>>(cnt, bucket, tiles, numTiles);
    k_ff1<<<MAX_TILES * 16, 256, 0, stream>>>(hnorm, d_in[4], d_in[5], flags, h1,
                                              tiles, numTiles, cnt, bucket);
    k_ff2<<<MAX_TILES * 4, 256, 0, stream>>>(h1, d_in[6], d_in[7], d_in[0], flags,
                                             alpha, d_out, tiles, numTiles, cnt, bucket);
}

// Round 4
// 587.536 us; speedup vs baseline: 1.2761x; 1.2761x over previous
//
#include <hip/hip_runtime.h>
#include <hip/hip_bf16.h>

// Problem constants: B=1, S=1024, D=1024, F=4096, E=8
#define TOK 1024
#define DIM 1024
#define FF  4096
#define NE  8
#define EPSV 1e-5f
#define MAX_TILES 72
#define BUCKET_STRIDE 1040   // 1024 + pad slack, per expert
#define NW (NE*FF*DIM)       // elements in W1 (== W2): 33,554,432

typedef __attribute__((ext_vector_type(8))) short short8;   // 8 bf16 = 4 VGPRs
typedef __attribute__((ext_vector_type(4))) float floatx4;

// -------- workspace layout (bytes) --------
#define OFF_W1B    0
#define OFF_W2B    (OFF_W1B + (size_t)NW*2)
#define OFF_HNORM  (OFF_W2B + (size_t)NW*2)
#define OFF_H1     (OFF_HNORM + TOK*DIM*2)
#define OFF_ALPHA  (OFF_H1 + TOK*FF*2)
#define OFF_CNT    (OFF_ALPHA + TOK*4)
#define OFF_NT     (OFF_CNT + NE*4)
#define OFF_TILES  (OFF_NT + 4)
#define OFF_BUCKET (OFF_TILES + MAX_TILES*4)
#define OFF_FLAGS  (OFF_BUCKET + NE*BUCKET_STRIDE*4)   // 9 ints
#define WS_NEED    (OFF_FLAGS + 16*4)

// fallback (no-convert) layout: weights stay in-place
#define FO_HNORM  0
#define FO_H1     (TOK*DIM*2)
#define FO_ALPHA  (FO_H1 + TOK*FF*2)
#define FO_CNT    (FO_ALPHA + TOK*4)
#define FO_NT     (FO_CNT + NE*4)
#define FO_TILES  (FO_NT + 4)
#define FO_BUCKET (FO_TILES + MAX_TILES*4)
#define FO_FLAGS  (FO_BUCKET + NE*BUCKET_STRIDE*4)

struct Ptr8 { const void* p[8]; };

// ---- dual-dtype helpers (flag: 1 = buffer is float32, 0 = bf16) ----
__device__ __forceinline__ float ldf(const void* p, size_t i, int f32) {
    if (f32) return ((const float*)p)[i];
    union { unsigned u; float f; } v;
    v.u = ((unsigned)((const unsigned short*)p)[i]) << 16;
    return v.f;
}

__device__ __forceinline__ short bf16rne(float f) {
    unsigned u = __float_as_uint(f);
    return (short)((u + 0x7FFFu + ((u >> 16) & 1u)) >> 16);
}

__device__ __forceinline__ short8 ldfrag8(const void* p, size_t i, int f32) {
    if (!f32) return *(const short8*)((const short*)p + i);
    const floatx4* fp = (const floatx4*)((const float*)p + i);
    const floatx4 a = fp[0], b = fp[1];
    short8 r;
    #pragma unroll
    for (int j = 0; j < 4; j++) { r[j] = bf16rne(a[j]); r[4 + j] = bf16rne(b[j]); }
    return r;
}

__device__ __forceinline__ void stout(void* p, size_t i, float v, int f32) {
    if (f32) ((float*)p)[i] = v;
    else ((__hip_bfloat16*)p)[i] = __float2bfloat16(v);
}

// Zero cnt + classify each input buffer's dtype by bit-pattern scan.
__global__ void k_init(Ptr8 ptrs, int* __restrict__ cnt, int* __restrict__ flags) {
    const int tid = threadIdx.x;
    if (tid < NE) cnt[tid] = 0;
    if (tid < 8) {
        const unsigned* w = (const unsigned*)ptrs.p[tid];
        int f32 = 0;
        for (int i = 0; i < 64; i++) {
            const unsigned v = w[i];
            if (v == 0x3F800000u) { f32 = 1; break; }   // exact f32 1.0 (e.g. gamma=ones)
            const unsigned lo = v & 0xFFFFu;
            if (lo != 0) {
                const unsigned e = (lo >> 7) & 0xFFu;
                if (e < 0x60u || e > 0x9Fu) { f32 = 1; break; }  // implausible bf16 exponent
            }
        }
        flags[tid] = f32;
    }
    __syncthreads();
    if (tid == 0) {
        int o = 0;
        for (int i = 0; i < 8; i++) o |= flags[i];
        flags[8] = o;   // output dtype via promotion: any f32 input -> f32 out
    }
}

// Convert one weight tensor (f32 or bf16 per flags[fidx]) to dense bf16 in ws.
__global__ __launch_bounds__(256) void k_convert(
    const void* __restrict__ W, const int* __restrict__ flags, int fidx,
    __hip_bfloat16* __restrict__ dst)
{
    const int f32 = flags[fidx];
    const int n8 = NW / 8;
    const int stride = gridDim.x * blockDim.x;
    for (int i = blockIdx.x * blockDim.x + threadIdx.x; i < n8; i += stride) {
        const short8 v = ldfrag8(W, (size_t)i * 8, f32);
        *(short8*)((short*)dst + (size_t)i * 8) = v;
    }
}

// One block (256 threads) per token: routing scores + argmax + sigmoid gate + LN.
__global__ __launch_bounds__(256) void k_route_ln(
    const void* __restrict__ x,
    const void* __restrict__ cent,
    const void* __restrict__ gamma,
    const void* __restrict__ beta,
    const int* __restrict__ flags,
    __hip_bfloat16* __restrict__ hnorm,
    float* __restrict__ alpha,
    int* __restrict__ cnt,
    int* __restrict__ bucket)
{
    __shared__ float centS[NE * DIM];
    __shared__ float part[4][10];
    __shared__ float bc[3];   // mu, rstd, expert-bits

    const int tid = threadIdx.x;
    const int t = blockIdx.x;
    const int fx = flags[0], fc = flags[1], fg = flags[2], fb = flags[3];

    for (int i = tid; i < NE * DIM; i += 256) centS[i] = ldf(cent, i, fc);

    float xv[4];
    #pragma unroll
    for (int i = 0; i < 4; i++)
        xv[i] = ldf(x, (size_t)t * DIM + tid + 256 * i, fx);

    __syncthreads();

    float s = 0.f, sq = 0.f, c[NE];
    #pragma unroll
    for (int e = 0; e < NE; e++) c[e] = 0.f;

    #pragma unroll
    for (int i = 0; i < 4; i++) {
        const int d = tid + 256 * i;
        const float f = xv[i];
        s += f; sq += f * f;
        #pragma unroll
        for (int e = 0; e < NE; e++)
            c[e] += f * centS[e * DIM + d];
    }

    #pragma unroll
    for (int o = 32; o > 0; o >>= 1) {
        s  += __shfl_xor(s, o);
        sq += __shfl_xor(sq, o);
        #pragma unroll
        for (int e = 0; e < NE; e++) c[e] += __shfl_xor(c[e], o);
    }
    const int wid = tid >> 6, lid = tid & 63;
    if (lid == 0) {
        part[wid][0] = s; part[wid][1] = sq;
        #pragma unroll
        for (int e = 0; e < NE; e++) part[wid][2 + e] = c[e];
    }
    __syncthreads();

    if (tid == 0) {
        float S = 0.f, SQ = 0.f, C[NE];
        #pragma unroll
        for (int e = 0; e < NE; e++) C[e] = 0.f;
        for (int w = 0; w < 4; w++) {
            S += part[w][0]; SQ += part[w][1];
            #pragma unroll
            for (int e = 0; e < NE; e++) C[e] += part[w][2 + e];
        }
        const float mu = S / (float)DIM;
        const float var = SQ / (float)DIM - mu * mu;
        const float rstd = rsqrtf(var + EPSV);
        int be = 0; float bs = C[0];
        #pragma unroll
        for (int e = 1; e < NE; e++)
            if (C[e] > bs) { bs = C[e]; be = e; }   // first-occurrence argmax
        alpha[t] = 1.f / (1.f + expf(-bs));
        const int pos = atomicAdd(&cnt[be], 1);
        bucket[be * BUCKET_STRIDE + pos] = t;
        bc[0] = mu; bc[1] = rstd; bc[2] = __int_as_float(be);
    }
    __syncthreads();

    const float mu = bc[0], rstd = bc[1];
    const int e = __float_as_int(bc[2]);
    #pragma unroll
    for (int i = 0; i < 4; i++) {
        const int d = tid + 256 * i;
        const float g = ldf(gamma, (size_t)e * DIM + d, fg);
        const float b = ldf(beta,  (size_t)e * DIM + d, fb);
        const float h = (xv[i] - mu) * rstd * g + b;
        hnorm[(size_t)t * DIM + d] = __float2bfloat16(h);
    }
}

// Single thread: build tile list, pad buckets to multiples of 16.
__global__ void k_plan(const int* __restrict__ cnt, int* __restrict__ bucket,
                       int* __restrict__ tiles, int* __restrict__ numTiles)
{
    if (threadIdx.x == 0 && blockIdx.x == 0) {
        int nt = 0;
        for (int e = 0; e < NE; e++) {
            const int n = cnt[e];
            const int mt = (n + 15) >> 4;
            const int fill = (n > 0) ? bucket[e * BUCKET_STRIDE] : 0;
            for (int i = n; i < mt * 16; i++) bucket[e * BUCKET_STRIDE + i] = fill;
            for (int i = 0; i < mt; i++) tiles[nt++] = (e << 16) | (i * 16);
        }
        *numTiles = nt;
    }
}

// ---------- FAST PATH: GEMMs over pre-converted bf16 weights ----------
__global__ __launch_bounds__(256) void k_ff1_b(
    const __hip_bfloat16* __restrict__ hnorm,
    const __hip_bfloat16* __restrict__ W1,     // converted, [E][FF][DIM]
    const void* __restrict__ b1,
    const int* __restrict__ flags,
    __hip_bfloat16* __restrict__ h1,
    const int* __restrict__ tiles,
    const int* __restrict__ numTiles,
    const int* __restrict__ cnt,
    const int* __restrict__ bucket)
{
    const int tile = blockIdx.x >> 4;
    if (tile >= *numTiles) return;
    const int fB = flags[5];
    const int nb = blockIdx.x & 15;
    const int td = tiles[tile];
    const int e = td >> 16;
    const int mbase = td & 0xffff;
    const int ne = cnt[e];

    const int wid = threadIdx.x >> 6;
    const int lane = threadIdx.x & 63;
    const int mr = lane & 15;
    const int q  = lane >> 4;

    const int tok = bucket[e * BUCKET_STRIDE + mbase + mr];
    const short* A = (const short*)hnorm + (size_t)tok * DIM + q * 8;
    const int n0 = nb * 256 + wid * 64;
    const short* Bp = (const short*)W1 + ((size_t)e * FF + n0 + mr) * DIM + q * 8;

    floatx4 acc[4];
    #pragma unroll
    for (int j = 0; j < 4; j++) acc[j] = (floatx4){0.f, 0.f, 0.f, 0.f};

    for (int k = 0; k < DIM; k += 32) {
        const short8 a  = *(const short8*)(A + k);
        const short8 b0 = *(const short8*)(Bp + k);
        const short8 b1v = *(const short8*)(Bp + (size_t)16 * DIM + k);
        const short8 b2v = *(const short8*)(Bp + (size_t)32 * DIM + k);
        const short8 b3v = *(const short8*)(Bp + (size_t)48 * DIM + k);
        acc[0] = __builtin_amdgcn_mfma_f32_16x16x32_bf16(a, b0,  acc[0], 0, 0, 0);
        acc[1] = __builtin_amdgcn_mfma_f32_16x16x32_bf16(a, b1v, acc[1], 0, 0, 0);
        acc[2] = __builtin_amdgcn_mfma_f32_16x16x32_bf16(a, b2v, acc[2], 0, 0, 0);
        acc[3] = __builtin_amdgcn_mfma_f32_16x16x32_bf16(a, b3v, acc[3], 0, 0, 0);
    }

    const int col = lane & 15;
    #pragma unroll
    for (int r = 0; r < 4; r++) {
        const int mi = q * 4 + r;
        const int slot = mbase + mi;
        if (slot < ne) {
            const int tr = bucket[e * BUCKET_STRIDE + slot];
            #pragma unroll
            for (int j = 0; j < 4; j++) {
                const int f = n0 + j * 16 + col;
                float v = acc[j][r] + ldf(b1, (size_t)e * FF + f, fB);
                v = v > 0.f ? v : 0.f;
                h1[(size_t)tr * FF + f] = __float2bfloat16(v);
            }
        }
    }
}

__global__ __launch_bounds__(256) void k_ff2_b(
    const __hip_bfloat16* __restrict__ h1,
    const __hip_bfloat16* __restrict__ W2,     // converted, [E][DIM][FF]
    const void* __restrict__ b2,
    const void* __restrict__ x,
    const int* __restrict__ flags,
    const float* __restrict__ alpha,
    void* __restrict__ out,
    const int* __restrict__ tiles,
    const int* __restrict__ numTiles,
    const int* __restrict__ cnt,
    const int* __restrict__ bucket)
{
    const int tile = blockIdx.x >> 2;
    if (tile >= *numTiles) return;
    const int fB = flags[7], fx = flags[0], fo = flags[8];
    const int nb = blockIdx.x & 3;
    const int td = tiles[tile];
    const int e = td >> 16;
    const int mbase = td & 0xffff;
    const int ne = cnt[e];

    const int wid = threadIdx.x >> 6;
    const int lane = threadIdx.x & 63;
    const int mr = lane & 15;
    const int q  = lane >> 4;

    const int tok = bucket[e * BUCKET_STRIDE + mbase + mr];
    const short* A = (const short*)h1 + (size_t)tok * FF + q * 8;
    const int n0 = nb * 256 + wid * 64;
    const short* Bp = (const short*)W2 + ((size_t)e * DIM + n0 + mr) * FF + q * 8;

    floatx4 acc[4];
    #pragma unroll
    for (int j = 0; j < 4; j++) acc[j] = (floatx4){0.f, 0.f, 0.f, 0.f};

    for (int k = 0; k < FF; k += 32) {
        const short8 a  = *(const short8*)(A + k);
        const short8 b0 = *(const short8*)(Bp + k);
        const short8 b1v = *(const short8*)(Bp + (size_t)16 * FF + k);
        const short8 b2v = *(const short8*)(Bp + (size_t)32 * FF + k);
        const short8 b3v = *(const short8*)(Bp + (size_t)48 * FF + k);
        acc[0] = __builtin_amdgcn_mfma_f32_16x16x32_bf16(a, b0,  acc[0], 0, 0, 0);
        acc[1] = __builtin_amdgcn_mfma_f32_16x16x32_bf16(a, b1v, acc[1], 0, 0, 0);
        acc[2] = __builtin_amdgcn_mfma_f32_16x16x32_bf16(a, b2v, acc[2], 0, 0, 0);
        acc[3] = __builtin_amdgcn_mfma_f32_16x16x32_bf16(a, b3v, acc[3], 0, 0, 0);
    }

    const int col = lane & 15;
    #pragma unroll
    for (int r = 0; r < 4; r++) {
        const int mi = q * 4 + r;
        const int slot = mbase + mi;
        if (slot < ne) {
            const int tr = bucket[e * BUCKET_STRIDE + slot];
            const float al = alpha[tr];
            #pragma unroll
            for (int j = 0; j < 4; j++) {
                const int d = n0 + j * 16 + col;
                const float xb = ldf(x, (size_t)tr * DIM + d, fx);
                const float v = xb + al * (acc[j][r] + ldf(b2, (size_t)e * DIM + d, fB));
                stout(out, (size_t)tr * DIM + d, v, fo);
            }
        }
    }
}

// ---------- FALLBACK PATH: flag-converting GEMMs (round-3 passing version) ----------
__global__ __launch_bounds__(256) void k_ff1_f(
    const __hip_bfloat16* __restrict__ hnorm,
    const void* __restrict__ W1,
    const void* __restrict__ b1,
    const int* __restrict__ flags,
    __hip_bfloat16* __restrict__ h1,
    const int* __restrict__ tiles,
    const int* __restrict__ numTiles,
    const int* __restrict__ cnt,
    const int* __restrict__ bucket)
{
    const int tile = blockIdx.x >> 4;
    if (tile >= *numTiles) return;
    const int fW = flags[4], fB = flags[5];
    const int nb = blockIdx.x & 15;
    const int td = tiles[tile];
    const int e = td >> 16;
    const int mbase = td & 0xffff;
    const int ne = cnt[e];

    const int wid = threadIdx.x >> 6;
    const int lane = threadIdx.x & 63;
    const int mr = lane & 15;
    const int q  = lane >> 4;

    const int tok = bucket[e * BUCKET_STRIDE + mbase + mr];
    const short* A = (const short*)hnorm + (size_t)tok * DIM + q * 8;
    const int n0 = nb * 256 + wid * 64;
    const size_t Brow = ((size_t)e * FF + n0 + mr) * DIM + q * 8;

    floatx4 acc[4];
    #pragma unroll
    for (int j = 0; j < 4; j++) acc[j] = (floatx4){0.f, 0.f, 0.f, 0.f};

    for (int k = 0; k < DIM; k += 32) {
        const short8 a  = *(const short8*)(A + k);
        const short8 b0 = ldfrag8(W1, Brow + k, fW);
        const short8 b1v = ldfrag8(W1, Brow + (size_t)16 * DIM + k, fW);
        const short8 b2v = ldfrag8(W1, Brow + (size_t)32 * DIM + k, fW);
        const short8 b3v = ldfrag8(W1, Brow + (size_t)48 * DIM + k, fW);
        acc[0] = __builtin_amdgcn_mfma_f32_16x16x32_bf16(a, b0,  acc[0], 0, 0, 0);
        acc[1] = __builtin_amdgcn_mfma_f32_16x16x32_bf16(a, b1v, acc[1], 0, 0, 0);
        acc[2] = __builtin_amdgcn_mfma_f32_16x16x32_bf16(a, b2v, acc[2], 0, 0, 0);
        acc[3] = __builtin_amdgcn_mfma_f32_16x16x32_bf16(a, b3v, acc[3], 0, 0, 0);
    }

    const int col = lane & 15;
    #pragma unroll
    for (int r = 0; r < 4; r++) {
        const int mi = q * 4 + r;
        const int slot = mbase + mi;
        if (slot < ne) {
            const int tr = bucket[e * BUCKET_STRIDE + slot];
            #pragma unroll
            for (int j = 0; j < 4; j++) {
                const int f = n0 + j * 16 + col;
                float v = acc[j][r] + ldf(b1, (size_t)e * FF + f, fB);
                v = v > 0.f ? v : 0.f;
                h1[(size_t)tr * FF + f] = __float2bfloat16(v);
            }
        }
    }
}

__global__ __launch_bounds__(256) void k_ff2_f(
    const __hip_bfloat16* __restrict__ h1,
    const void* __restrict__ W2,
    const void* __restrict__ b2,
    const void* __restrict__ x,
    const int* __restrict__ flags,
    const float* __restrict__ alpha,
    void* __restrict__ out,
    const int* __restrict__ tiles,
    const int* __restrict__ numTiles,
    const int* __restrict__ cnt,
    const int* __restrict__ bucket)
{
    const int tile = blockIdx.x >> 2;
    if (tile >= *numTiles) return;
    const int fW = flags[6], fB = flags[7], fx = flags[0], fo = flags[8];
    const int nb = blockIdx.x & 3;
    const int td = tiles[tile];
    const int e = td >> 16;
    const int mbase = td & 0xffff;
    const int ne = cnt[e];

    const int wid = threadIdx.x >> 6;
    const int lane = threadIdx.x & 63;
    const int mr = lane & 15;
    const int q  = lane >> 4;

    const int tok = bucket[e * BUCKET_STRIDE + mbase + mr];
    const short* A = (const short*)h1 + (size_t)tok * FF + q * 8;
    const int n0 = nb * 256 + wid * 64;
    const size_t Brow = ((size_t)e * DIM + n0 + mr) * FF + q * 8;

    floatx4 acc[4];
    #pragma unroll
    for (int j = 0; j < 4; j++) acc[j] = (floatx4){0.f, 0.f, 0.f, 0.f};

    for (int k = 0; k < FF; k += 32) {
        const short8 a  = *(const short8*)(A + k);
        const short8 b0 = ldfrag8(W2, Brow + k, fW);
        const short8 b1v = ldfrag8(W2, Brow + (size_t)16 * FF + k, fW);
        const short8 b2v = ldfrag8(W2, Brow + (size_t)32 * FF + k, fW);
        const short8 b3v = ldfrag8(W2, Brow + (size_t)48 * FF + k, fW);
        acc[0] = __builtin_amdgcn_mfma_f32_16x16x32_bf16(a, b0,  acc[0], 0, 0, 0);
        acc[1] = __builtin_amdgcn_mfma_f32_16x16x32_bf16(a, b1v, acc[1], 0, 0, 0);
        acc[2] = __builtin_amdgcn_mfma_f32_16x16x32_bf16(a, b2v, acc[2], 0, 0, 0);
        acc[3] = __builtin_amdgcn_mfma_f32_16x16x32_bf16(a, b3v, acc[3], 0, 0, 0);
    }

    const int col = lane & 15;
    #pragma unroll
    for (int r = 0; r < 4; r++) {
        const int mi = q * 4 + r;
        const int slot = mbase + mi;
        if (slot < ne) {
            const int tr = bucket[e * BUCKET_STRIDE + slot];
            const float al = alpha[tr];
            #pragma unroll
            for (int j = 0; j < 4; j++) {
                const int d = n0 + j * 16 + col;
                const float xb = ldf(x, (size_t)tr * DIM + d, fx);
                const float v = xb + al * (acc[j][r] + ldf(b2, (size_t)e * DIM + d, fB));
                stout(out, (size_t)tr * DIM + d, v, fo);
            }
        }
    }
}

extern "C" void kernel_launch(void* const* d_in, const int* in_sizes, int n_in,
                              void* d_out, int out_size, void* d_ws, size_t ws_size,
                              hipStream_t stream) {
    char* ws = (char*)d_ws;
    Ptr8 ptrs;
    for (int i = 0; i < 8; i++) ptrs.p[i] = d_in[i];

    if (ws_size >= (size_t)WS_NEED) {
        __hip_bfloat16* w1b   = (__hip_bfloat16*)(ws + OFF_W1B);
        __hip_bfloat16* w2b   = (__hip_bfloat16*)(ws + OFF_W2B);
        __hip_bfloat16* hnorm = (__hip_bfloat16*)(ws + OFF_HNORM);
        __hip_bfloat16* h1    = (__hip_bfloat16*)(ws + OFF_H1);
        float* alpha          = (float*)(ws + OFF_ALPHA);
        int* cnt              = (int*)(ws + OFF_CNT);
        int* numTiles         = (int*)(ws + OFF_NT);
        int* tiles            = (int*)(ws + OFF_TILES);
        int* bucket           = (int*)(ws + OFF_BUCKET);
        int* flags            = (int*)(ws + OFF_FLAGS);

        k_init<<<1, 64, 0, stream>>>(ptrs, cnt, flags);
        k_convert<<<4096, 256, 0, stream>>>(d_in[4], flags, 4, w1b);
        k_route_ln<<<TOK, 256, 0, stream>>>(d_in[0], d_in[1], d_in[2], d_in[3], flags,
                                            hnorm, alpha, cnt, bucket);
        k_plan<<<1, 64, 0, stream>>>(cnt, bucket, tiles, numTiles);
        k_ff1_b<<<MAX_TILES * 16, 256, 0, stream>>>(hnorm, w1b, d_in[5], flags, h1,
                                                    tiles, numTiles, cnt, bucket);
        k_convert<<<4096, 256, 0, stream>>>(d_in[6], flags, 6, w2b);
        k_ff2_b<<<MAX_TILES * 4, 256, 0, stream>>>(h1, w2b, d_in[7], d_in[0], flags,
                                                   alpha, d_out, tiles, numTiles, cnt, bucket);
    } else {
        __hip_bfloat16* hnorm = (__hip_bfloat16*)(ws + FO_HNORM);
        __hip_bfloat16* h1    = (__hip_bfloat16*)(ws + FO_H1);
        float* alpha          = (float*)(ws + FO_ALPHA);
        int* cnt              = (int*)(ws + FO_CNT);
        int* numTiles         = (int*)(ws + FO_NT);
        int* tiles            = (int*)(ws + FO_TILES);
        int* bucket           = (int*)(ws + FO_BUCKET);
        int* flags            = (int*)(ws + FO_FLAGS);

        k_init<<<1, 64, 0, stream>>>(ptrs, cnt, flags);
        k_route_ln<<<TOK, 256, 0, stream>>>(d_in[0], d_in[1], d_in[2], d_in[3], flags,
                                            hnorm, alpha, cnt, bucket);
        k_plan<<<1, 64, 0, stream>>>(cnt, bucket, tiles, numTiles);
        k_ff1_f<<<MAX_TILES * 16, 256, 0, stream>>>(hnorm, d_in[4], d_in[5], flags, h1,
                                                    tiles, numTiles, cnt, bucket);
        k_ff2_f<<<MAX_TILES * 4, 256, 0, stream>>>(h1, d_in[6], d_in[7], d_in[0], flags,
                                                   alpha, d_out, tiles, numTiles, cnt, bucket);
    }
}